// Round 8
// baseline (373.473 us; speedup 1.0000x reference)
//
#include <hip/hip_runtime.h>

typedef __attribute__((ext_vector_type(8))) short bf16x8;
typedef __attribute__((ext_vector_type(4))) float f32x4;
typedef __attribute__((ext_vector_type(4))) short short4v;
typedef __attribute__((ext_vector_type(4))) unsigned int u32x4;

#define DEVFN static __device__ __forceinline__

DEVFN short f2bf(float f) {
  unsigned int u = __builtin_bit_cast(unsigned int, f);
  unsigned int r = (u + 0x7FFFu + ((u >> 16) & 1u)) >> 16;   // RNE
  return (short)r;
}

DEVFN unsigned int pack2bf(float a, float b) {
  unsigned int lo = (unsigned int)(unsigned short)f2bf(a);
  unsigned int hi = (unsigned int)(unsigned short)f2bf(b);
  return lo | (hi << 16);
}

DEVFN f32x4 mfma_bf16(bf16x8 a, bf16x8 b, f32x4 c) {
  return __builtin_amdgcn_mfma_f32_16x16x32_bf16(a, b, c, 0, 0, 0);
}

DEVFN f32x4 zero4() { f32x4 z = {0.f, 0.f, 0.f, 0.f}; return z; }
DEVFN bf16x8 zero8() { bf16x8 z = {0,0,0,0,0,0,0,0}; return z; }

DEVFN void gload_lds16(const void* g, void* l) {
  __builtin_amdgcn_global_load_lds(
      (const __attribute__((address_space(1))) unsigned int*)g,
      (__attribute__((address_space(3))) unsigned int*)l, 16, 0, 0);
}

DEVFN bf16x8 lds8(const short* p) {
  short4v lo = *reinterpret_cast<const short4v*>(p);
  short4v hi = *reinterpret_cast<const short4v*>(p + 4);
  bf16x8 r;
  r[0] = lo[0]; r[1] = lo[1]; r[2] = lo[2]; r[3] = lo[3];
  r[4] = hi[0]; r[5] = hi[1]; r[6] = hi[2]; r[7] = hi[3];
  return r;
}

// ---------------------------------------------------------------------------
// Weight pack: fold BN scale, cvt bf16, fragment-major layout
// ---------------------------------------------------------------------------
__global__ void pack_w_k(const float* __restrict__ w, const float* __restrict__ g,
                         const float* __restrict__ b, const float* __restrict__ m,
                         const float* __restrict__ v, short* __restrict__ pk,
                         float* __restrict__ bias, int O) {
  const int t = blockIdx.x * 256 + threadIdx.x;
  const int nt = O >> 4;
  const int total = nt * 8 * 64;
  if (t < total) {
    int lane = t & 63;
    int j = (t >> 6) % nt;
    int c = (t >> 6) / nt;
    int row = j * 16 + (lane & 15);
    int col = c * 32 + (lane >> 4) * 8;
    float s = g[row] * rsqrtf(v[row] + 1e-5f);
    const float* wp = w + (size_t)row * 256 + col;
    short* o = pk + (size_t)t * 8;
#pragma unroll
    for (int e = 0; e < 8; ++e) o[e] = f2bf(wp[e] * s);
  }
  if (t < O) {
    float s = g[t] * rsqrtf(v[t] + 1e-5f);
    bias[t] = b[t] - m[t] * s;
  }
}

// ---------------------------------------------------------------------------
// x -> bf16 row-major pack. grid = 12544 x 256, one bf16x8 per thread.
// ---------------------------------------------------------------------------
__global__ __launch_bounds__(256) void pack_x_k(const float* __restrict__ x,
                                                short* __restrict__ xbf) {
  const size_t t = (size_t)blockIdx.x * 256 + threadIdx.x;
  const float* src = x + t * 8;
  float4 u0 = *reinterpret_cast<const float4*>(src);
  float4 u1 = *reinterpret_cast<const float4*>(src + 4);
  bf16x8 vv;
  vv[0] = f2bf(u0.x); vv[1] = f2bf(u0.y); vv[2] = f2bf(u0.z); vv[3] = f2bf(u0.w);
  vv[4] = f2bf(u1.x); vv[5] = f2bf(u1.y); vv[6] = f2bf(u1.z); vv[7] = f2bf(u1.w);
  *reinterpret_cast<bf16x8*>(xbf + t * 8) = vv;
}

// ---------------------------------------------------------------------------
// ab_full[h][q][n] = ab_table[h][bias_idxs[q][n]]
// ---------------------------------------------------------------------------
__global__ void ab_gather_k(const float* __restrict__ tab,
                            const int* __restrict__ idxs,
                            float* __restrict__ out, int n_off) {
  const int hq = blockIdx.x;
  const int h = hq / 49, q = hq % 49;
  const int t = threadIdx.x;
  if (t < 196)
    out[(size_t)hq * 196 + t] = tab[h * n_off + idxs[q * 196 + t]];
}

// ---------------------------------------------------------------------------
// Fused per-(b, head-pair) kernel. grid = 2048 (b*4 + hp), 256 thr, 4 waves.
// Small LDS (23.6 KB) -> multiple blocks/CU; serial phases per block, cross-
// block overlap supplies the latency hiding. x read from pre-packed bf16 (L3).
// ---------------------------------------------------------------------------
__global__ __launch_bounds__(256) void fused3_k(
    const short* __restrict__ xbf,
    const short* __restrict__ pkv, const float* __restrict__ bkv,
    const short* __restrict__ pq,  const float* __restrict__ bq_,
    const float* __restrict__ ab,  short* __restrict__ at_out) {
  __shared__ short qs[1568];    // [2 heads][49 rows][16 kd]
  __shared__ short ks[3920];    // [196][20]
  __shared__ short vs[6368];    // [32][198] + 32 guard
  const int bid = blockIdx.x;
  const int b = bid >> 2, h0 = (bid & 3) * 2;
  const int tid = threadIdx.x, w = tid >> 6, lane = tid & 63;
  const int l15 = lane & 15, g = lane >> 4;

  // zero V pads (cols 196/197 each row) + tail guard
  if (tid < 64) vs[(tid >> 1) * 198 + 196 + (tid & 1)] = 0;
  else if (tid < 96) vs[6336 + (tid - 64)] = 0;

  const short* xb = xbf + (size_t)b * 196 * 256;

  // ---- P1: q-gemm for heads h0, h0+1 (wave w = M-tile w) ----
  {
    f32x4 qa0 = zero4(), qa1 = zero4();
    int qi = w * 16 + l15; if (qi > 48) qi = 48;
    int xr = 28 * (qi / 7) + 2 * (qi % 7);
    const short* xrp = xb + xr * 256 + g * 8;
#pragma unroll
    for (int c = 0; c < 8; ++c) {
      bf16x8 a = *reinterpret_cast<const bf16x8*>(xrp + c * 32);
      bf16x8 w0 = *reinterpret_cast<const bf16x8*>(pq + ((size_t)(c * 8 + h0) * 64 + lane) * 8);
      bf16x8 w1 = *reinterpret_cast<const bf16x8*>(pq + ((size_t)(c * 8 + h0 + 1) * 64 + lane) * 8);
      qa0 = mfma_bf16(a, w0, qa0);
      qa1 = mfma_bf16(a, w1, qa1);
    }
    float b0 = bq_[h0 * 16 + l15], b1 = bq_[(h0 + 1) * 16 + l15];
#pragma unroll
    for (int r = 0; r < 4; ++r) {
      int row = w * 16 + g * 4 + r;
      if (row < 49) {
        qs[row * 16 + l15] = f2bf(qa0[r] + b0);
        qs[(49 + row) * 16 + l15] = f2bf(qa1[r] + b1);
      }
    }
  }
  __syncthreads();

#pragma unroll 1
  for (int hh = 0; hh < 2; ++hh) {
    const int h = h0 + hh;

    // ---- kv-gemm for head h: wave w owns tiles {w, w+4, w+8, w+12} ----
    {
      f32x4 aK[4], a0[4], a1[4];
#pragma unroll
      for (int t = 0; t < 4; ++t) { aK[t] = zero4(); a0[t] = zero4(); a1[t] = zero4(); }
#pragma unroll
      for (int c = 0; c < 8; ++c) {
        bf16x8 wf0 = *reinterpret_cast<const bf16x8*>(pkv + ((size_t)(c * 24 + 3 * h) * 64 + lane) * 8);
        bf16x8 wf1 = *reinterpret_cast<const bf16x8*>(pkv + ((size_t)(c * 24 + 3 * h + 1) * 64 + lane) * 8);
        bf16x8 wf2 = *reinterpret_cast<const bf16x8*>(pkv + ((size_t)(c * 24 + 3 * h + 2) * 64 + lane) * 8);
#pragma unroll
        for (int ti = 0; ti < 4; ++ti) {
          const int tile = w + ti * 4;
          if (tile < 13) {
            int xr = tile * 16 + l15; if (xr > 195) xr = 195;
            bf16x8 a = *reinterpret_cast<const bf16x8*>(xb + xr * 256 + c * 32 + g * 8);
            aK[ti] = mfma_bf16(a, wf0, aK[ti]);    // K[n][kd]
            a0[ti] = mfma_bf16(wf1, a, a0[ti]);    // V^T[d0..15][n]
            a1[ti] = mfma_bf16(wf2, a, a1[ti]);    // V^T[d16..31][n]
          }
        }
      }
      float  bvK = bkv[3 * h * 16 + l15];
      float4 bv0 = *reinterpret_cast<const float4*>(bkv + (3 * h + 1) * 16 + g * 4);
      float4 bv1 = *reinterpret_cast<const float4*>(bkv + (3 * h + 2) * 16 + g * 4);
#pragma unroll
      for (int ti = 0; ti < 4; ++ti) {
        const int tile = w + ti * 4;
        if (tile < 13) {
#pragma unroll
          for (int r = 0; r < 4; ++r) {
            int n = tile * 16 + g * 4 + r;
            if (n < 196) ks[n * 20 + l15] = f2bf(aK[ti][r] + bvK);
          }
          int nv = tile * 16 + l15;
          if (nv < 196) {
#pragma unroll
            for (int r = 0; r < 4; ++r)
              vs[(g * 4 + r) * 198 + nv] = f2bf(a0[ti][r] + bv0[r]);
#pragma unroll
            for (int r = 0; r < 4; ++r)
              vs[(16 + g * 4 + r) * 198 + nv] = f2bf(a1[ti][r] + bv1[r]);
          }
        }
      }
    }
    __syncthreads();   // k/v slab ready

    // ---- attention for head h (wave w = q-tile w) ----
    {
      int qm = w * 16 + l15; if (qm > 48) qm = 48;
      bf16x8 bq = zero8();
      if (g < 2) bq = lds8(qs + (hh * 49 + qm) * 16 + g * 8);

      f32x4 s[13];
#pragma unroll
      for (int t = 0; t < 13; ++t) {
        int n_a = (t >> 1) * 32 + (l15 >> 2) * 8 + (t & 1) * 4 + (l15 & 3);
        bf16x8 ak = zero8();
        if (g < 2 && n_a < 196) ak = lds8(ks + n_a * 20 + g * 8);
        s[t] = mfma_bf16(ak, bq, zero4());
      }

      const float* abrow = ab + ((size_t)h * 49 + qm) * 196;
#pragma unroll
      for (int t = 0; t < 13; ++t) {
        int nb = (t >> 1) * 32 + g * 8 + (t & 1) * 4;
        if (nb < 196) {
          const float4 bi = *reinterpret_cast<const float4*>(abrow + nb);
          s[t][0] = s[t][0] * 0.25f + bi.x;
          s[t][1] = s[t][1] * 0.25f + bi.y;
          s[t][2] = s[t][2] * 0.25f + bi.z;
          s[t][3] = s[t][3] * 0.25f + bi.w;
        } else {
          s[t][0] = -1e30f; s[t][1] = -1e30f; s[t][2] = -1e30f; s[t][3] = -1e30f;
        }
      }

      float mx = s[0][0];
#pragma unroll
      for (int t = 0; t < 13; ++t)
        mx = fmaxf(mx, fmaxf(fmaxf(s[t][0], s[t][1]), fmaxf(s[t][2], s[t][3])));
      mx = fmaxf(mx, __shfl_xor(mx, 16, 64));
      mx = fmaxf(mx, __shfl_xor(mx, 32, 64));
      float sum = 0.f;
#pragma unroll
      for (int t = 0; t < 13; ++t) {
#pragma unroll
        for (int r = 0; r < 4; ++r) {
          float e = __expf(s[t][r] - mx);
          s[t][r] = e;
          sum += e;
        }
      }
      sum += __shfl_xor(sum, 16, 64);
      sum += __shfl_xor(sum, 32, 64);
      const float inv = 1.f / sum;

      unsigned int pkr[14][2];
#pragma unroll
      for (int t = 0; t < 13; ++t) {
        pkr[t][0] = pack2bf(s[t][0] * inv, s[t][1] * inv);
        pkr[t][1] = pack2bf(s[t][2] * inv, s[t][3] * inv);
      }
      pkr[13][0] = 0u; pkr[13][1] = 0u;

      f32x4 o0 = zero4(), o1 = zero4();
#pragma unroll
      for (int c = 0; c < 7; ++c) {
        u32x4 bp_u;
        bp_u[0] = pkr[2 * c][0];     bp_u[1] = pkr[2 * c][1];
        bp_u[2] = pkr[2 * c + 1][0]; bp_u[3] = pkr[2 * c + 1][1];
        bf16x8 bp = __builtin_bit_cast(bf16x8, bp_u);
        bf16x8 v0 = lds8(vs + l15 * 198 + c * 32 + g * 8);
        bf16x8 v1 = lds8(vs + (16 + l15) * 198 + c * 32 + g * 8);
        o0 = mfma_bf16(bp, v0, o0);   // O[q][d]
        o1 = mfma_bf16(bp, v1, o1);
      }

#pragma unroll
      for (int r = 0; r < 4; ++r) {
        int q2 = w * 16 + g * 4 + r;
        if (q2 < 49) {
          float x0 = o0[r];
          float hh0 = x0 * fminf(fmaxf(x0 + 3.f, 0.f), 6.f) * (1.f / 6.f);
          float x1 = o1[r];
          float hh1 = x1 * fminf(fmaxf(x1 + 3.f, 0.f), 6.f) * (1.f / 6.f);
          short* op = at_out + ((size_t)b * 49 + q2) * 256 + h * 32;
          op[l15] = f2bf(hh0);
          op[16 + l15] = f2bf(hh1);
        }
      }
    }
    __syncthreads();   // slab consumed before next head overwrites
  }
}

// ---------------------------------------------------------------------------
// Projection: out = at @ pk_p + bias -> f32 (B*49, 512). grid = 392*2.
// ---------------------------------------------------------------------------
__global__ __launch_bounds__(256) void p_gemm2(
    const short* __restrict__ a_in, const short* __restrict__ pk,
    const float* __restrict__ bias, float* __restrict__ out) {
  __shared__ short bs[16 * 512];
  __shared__ float sb[256];
  const int tid = threadIdx.x, w_id = tid >> 6, lane = tid & 63;
  const int l15 = lane & 15, gq = lane >> 4;
  const int half = blockIdx.x & 1;
  const int mt = blockIdx.x >> 1;
  for (int i = tid; i < 256; i += 256) sb[i] = bias[half * 256 + i];
  const int arow = mt * 64 + w_id * 16 + l15;
  const short* arp = a_in + (size_t)arow * 256;

  f32x4 acc[16];
#pragma unroll
  for (int j = 0; j < 16; ++j) acc[j] = zero4();

  for (int c = 0; c < 8; ++c) {
    for (int seg = w_id; seg < 16; seg += 4)
      gload_lds16(pk + ((size_t)(c * 32 + half * 16 + seg) * 64 + lane) * 8,
                  &bs[seg * 512]);
    bf16x8 a = *reinterpret_cast<const bf16x8*>(arp + c * 32 + gq * 8);
    __syncthreads();
#pragma unroll
    for (int j = 0; j < 16; ++j) {
      bf16x8 bj = *reinterpret_cast<const bf16x8*>(&bs[(j * 64 + lane) * 8]);
      acc[j] = mfma_bf16(a, bj, acc[j]);
    }
    __syncthreads();
  }
  const int orow = mt * 64 + w_id * 16 + gq * 4;
#pragma unroll
  for (int j = 0; j < 16; ++j) {
    int chl = j * 16 + l15;
    float bb = sb[chl];
    int och = half * 256 + chl;
#pragma unroll
    for (int r = 0; r < 4; ++r)
      out[(size_t)(orow + r) * 512 + och] = acc[j][r] + bb;
  }
}

// ---------------------------------------------------------------------------
extern "C" void kernel_launch(void* const* d_in, const int* in_sizes, int n_in,
                              void* d_out, int out_size, void* d_ws, size_t ws_size,
                              hipStream_t stream) {
  const float* x    = (const float*)d_in[0];
  const float* w_kv = (const float*)d_in[1];
  const float* kv_g = (const float*)d_in[2];
  const float* kv_b = (const float*)d_in[3];
  const float* kv_m = (const float*)d_in[4];
  const float* kv_v = (const float*)d_in[5];
  const float* w_q  = (const float*)d_in[6];
  const float* q_g  = (const float*)d_in[7];
  const float* q_b  = (const float*)d_in[8];
  const float* q_m  = (const float*)d_in[9];
  const float* q_v  = (const float*)d_in[10];
  const float* w_p  = (const float*)d_in[11];
  const float* p_g  = (const float*)d_in[12];
  const float* p_b  = (const float*)d_in[13];
  const float* p_m  = (const float*)d_in[14];
  const float* p_v  = (const float*)d_in[15];
  const float* ab_t = (const float*)d_in[16];
  const int*   idxs = (const int*)d_in[17];
  const int n_off = in_sizes[16] / 8;

  char* ws = (char*)d_ws;
  short* pk_kv = (short*)(ws);                 //    196,608
  short* pk_q  = (short*)(ws + 196608);        //     65,536
  short* pk_p  = (short*)(ws + 262144);        //    262,144
  float* bs_kv = (float*)(ws + 524288);        //      1,536
  float* bs_q  = (float*)(ws + 525824);        //        512
  float* bs_p  = (float*)(ws + 526336);        //      2,048
  float* ab_ws = (float*)(ws + 528384);        //    307,328 -> 835,712
  short* at_ws = (short*)(ws + 835712);        // 12,845,056 -> 13,680,768
  short* x_bf  = (short*)(ws + 13680768);      // 51,380,224 -> 65,060,992

  pack_w_k<<<dim3(48), dim3(256), 0, stream>>>(w_kv, kv_g, kv_b, kv_m, kv_v, pk_kv, bs_kv, 384);
  pack_w_k<<<dim3(16), dim3(256), 0, stream>>>(w_q, q_g, q_b, q_m, q_v, pk_q, bs_q, 128);
  pack_w_k<<<dim3(64), dim3(256), 0, stream>>>(w_p, p_g, p_b, p_m, p_v, pk_p, bs_p, 512);
  ab_gather_k<<<dim3(392), dim3(256), 0, stream>>>(ab_t, idxs, ab_ws, n_off);
  pack_x_k<<<dim3(12544), dim3(256), 0, stream>>>(x, x_bf);

  fused3_k<<<dim3(2048), dim3(256), 0, stream>>>(
      x_bf, pk_kv, bs_kv, pk_q, bs_q, ab_ws, at_ws);
  p_gemm2<<<dim3(784), dim3(256), 0, stream>>>(at_ws, pk_p, bs_p, (float*)d_out);
}

// Round 9
// 153.970 us; speedup vs baseline: 2.4256x; 2.4256x over previous
//
#include <hip/hip_runtime.h>

typedef __attribute__((ext_vector_type(8))) short bf16x8;
typedef __attribute__((ext_vector_type(4))) float f32x4;
typedef __attribute__((ext_vector_type(4))) short short4v;
typedef __attribute__((ext_vector_type(4))) unsigned int u32x4;

#define DEVFN static __device__ __forceinline__

DEVFN short f2bf(float f) {
  unsigned int u = __builtin_bit_cast(unsigned int, f);
  unsigned int r = (u + 0x7FFFu + ((u >> 16) & 1u)) >> 16;   // RNE
  return (short)r;
}

DEVFN unsigned int pack2bf(float a, float b) {
  unsigned int lo = (unsigned int)(unsigned short)f2bf(a);
  unsigned int hi = (unsigned int)(unsigned short)f2bf(b);
  return lo | (hi << 16);
}

DEVFN f32x4 mfma_bf16(bf16x8 a, bf16x8 b, f32x4 c) {
  return __builtin_amdgcn_mfma_f32_16x16x32_bf16(a, b, c, 0, 0, 0);
}

DEVFN f32x4 zero4() { f32x4 z = {0.f, 0.f, 0.f, 0.f}; return z; }
DEVFN bf16x8 zero8() { bf16x8 z = {0,0,0,0,0,0,0,0}; return z; }

DEVFN void gload_lds16(const void* g, void* l) {
  __builtin_amdgcn_global_load_lds(
      (const __attribute__((address_space(1))) unsigned int*)g,
      (__attribute__((address_space(3))) unsigned int*)l, 16, 0, 0);
}

DEVFN bf16x8 lds8(const short* p) {
  short4v lo = *reinterpret_cast<const short4v*>(p);
  short4v hi = *reinterpret_cast<const short4v*>(p + 4);
  bf16x8 r;
  r[0] = lo[0]; r[1] = lo[1]; r[2] = lo[2]; r[3] = lo[3];
  r[4] = hi[0]; r[5] = hi[1]; r[6] = hi[2]; r[7] = hi[3];
  return r;
}

// ---------------------------------------------------------------------------
// Weight pack: fold BN scale, cvt bf16, fragment-major layout
// pk[((c*(O/16)+j)*64+lane)*8+e] = w[j*16+(lane&15)][c*32+(lane>>4)*8+e]*s
// ---------------------------------------------------------------------------
__global__ void pack_w_k(const float* __restrict__ w, const float* __restrict__ g,
                         const float* __restrict__ b, const float* __restrict__ m,
                         const float* __restrict__ v, short* __restrict__ pk,
                         float* __restrict__ bias, int O) {
  const int t = blockIdx.x * 256 + threadIdx.x;
  const int nt = O >> 4;
  const int total = nt * 8 * 64;
  if (t < total) {
    int lane = t & 63;
    int j = (t >> 6) % nt;
    int c = (t >> 6) / nt;
    int row = j * 16 + (lane & 15);
    int col = c * 32 + (lane >> 4) * 8;
    float s = g[row] * rsqrtf(v[row] + 1e-5f);
    const float* wp = w + (size_t)row * 256 + col;
    short* o = pk + (size_t)t * 8;
#pragma unroll
    for (int e = 0; e < 8; ++e) o[e] = f2bf(wp[e] * s);
  }
  if (t < O) {
    float s = g[t] * rsqrtf(v[t] + 1e-5f);
    bias[t] = b[t] - m[t] * s;
  }
}

// ---------------------------------------------------------------------------
// ab_full[h][q][n] = ab_table[h][bias_idxs[q][n]]
// ---------------------------------------------------------------------------
__global__ void ab_gather_k(const float* __restrict__ tab,
                            const int* __restrict__ idxs,
                            float* __restrict__ out, int n_off) {
  const int hq = blockIdx.x;
  const int h = hq / 49, q = hq % 49;
  const int t = threadIdx.x;
  if (t < 196)
    out[(size_t)hq * 196 + t] = tab[h * n_off + idxs[q * 196 + t]];
}

// ---------------------------------------------------------------------------
// Kernel 1 (NEW): kv gemm, stage-x-once + single barrier + no further syncs.
// 512 thr (8 waves); wave w == head w computes {K, V0, V1} x 4 m-subtiles.
// x-tile (64 rows) staged swizzled in 32 KB LDS; weight frags streamed from
// L2 (coalesced 1 KB loads). grid = 1568.
// ---------------------------------------------------------------------------
__global__ __launch_bounds__(512, 4) void kv_gemm5(
    const float* __restrict__ x, const short* __restrict__ pk,
    const float* __restrict__ bias, short* __restrict__ k_out,
    short* __restrict__ vT_out) {
  __shared__ short xs2[16384];   // 64 rows x 256 bf16, swizzled, 32 KB
  const int tid = threadIdx.x, w = tid >> 6, lane = tid & 63;
  const int l15 = lane & 15, g = lane >> 4;
  const int mt = blockIdx.x;

  // ---- stage x-tile: coalesced f32 reads, cvt, swizzled b128 LDS stores ----
  const float* xb = x + (size_t)mt * 64 * 256;
#pragma unroll
  for (int it = 0; it < 4; ++it) {
    int i = it * 512 + tid;            // chunk: row = i>>5, gc = i&31
    int row = i >> 5, gc = i & 31;
    const float* src = xb + row * 256 + gc * 8;
    float4 u0 = *reinterpret_cast<const float4*>(src);
    float4 u1 = *reinterpret_cast<const float4*>(src + 4);
    bf16x8 vv;
    vv[0] = f2bf(u0.x); vv[1] = f2bf(u0.y); vv[2] = f2bf(u0.z); vv[3] = f2bf(u0.w);
    vv[4] = f2bf(u1.x); vv[5] = f2bf(u1.y); vv[6] = f2bf(u1.z); vv[7] = f2bf(u1.w);
    *reinterpret_cast<bf16x8*>(reinterpret_cast<char*>(xs2) + row * 512 +
                               ((gc * 16) ^ ((row & 7) << 4))) = vv;
  }
  __syncthreads();   // the ONLY barrier

  // ---- main loop: no syncs; LDS is read-only from here ----
  f32x4 acc[4][3];
#pragma unroll
  for (int m = 0; m < 4; ++m) {
    acc[m][0] = zero4(); acc[m][1] = zero4(); acc[m][2] = zero4();
  }
  const int swz = (l15 & 7) << 4;      // row&7 == l15&7 for all m-subtiles
#pragma unroll
  for (int c = 0; c < 8; ++c) {
    bf16x8 wf0 = *reinterpret_cast<const bf16x8*>(pk + ((size_t)(c * 24 + 3 * w) * 64 + lane) * 8);
    bf16x8 wf1 = *reinterpret_cast<const bf16x8*>(pk + ((size_t)(c * 24 + 3 * w + 1) * 64 + lane) * 8);
    bf16x8 wf2 = *reinterpret_cast<const bf16x8*>(pk + ((size_t)(c * 24 + 3 * w + 2) * 64 + lane) * 8);
#pragma unroll
    for (int m = 0; m < 4; ++m) {
      const int row = m * 16 + l15;
      bf16x8 a = *reinterpret_cast<const bf16x8*>(
          reinterpret_cast<const char*>(xs2) + row * 512 +
          ((c * 64 + g * 16) ^ swz));
      acc[m][0] = mfma_bf16(a, wf0, acc[m][0]);
      acc[m][1] = mfma_bf16(a, wf1, acc[m][1]);
      acc[m][2] = mfma_bf16(a, wf2, acc[m][2]);
    }
  }

  // ---- epilogue: K -> [b][h][196][16], V^T -> [b][h][32][196] ----
  const float bvK = bias[(3 * w) * 16 + l15];
  const float bv1 = bias[(3 * w + 1) * 16 + l15];
  const float bv2 = bias[(3 * w + 2) * 16 + l15];
#pragma unroll
  for (int m = 0; m < 4; ++m) {
    const int row0 = mt * 64 + m * 16 + g * 4;
    const int bb_ = row0 / 196, n0 = row0 % 196;   // 4-row quad never straddles
    short* kp = k_out + ((size_t)(bb_ * 8 + w) * 196 + n0) * 16 + l15;
#pragma unroll
    for (int r = 0; r < 4; ++r) kp[r * 16] = f2bf(acc[m][0][r] + bvK);
    short4v sv;
#pragma unroll
    for (int r = 0; r < 4; ++r) sv[r] = f2bf(acc[m][1][r] + bv1);
    *reinterpret_cast<short4v*>(
        vT_out + ((size_t)(bb_ * 8 + w) * 32 + l15) * 196 + n0) = sv;
#pragma unroll
    for (int r = 0; r < 4; ++r) sv[r] = f2bf(acc[m][2][r] + bv2);
    *reinterpret_cast<short4v*>(
        vT_out + ((size_t)(bb_ * 8 + w) * 32 + 16 + l15) * 196 + n0) = sv;
  }
}

// ---------------------------------------------------------------------------
// Kernel 2: q = xs @ pk_q + bias -> bf16 (B*49, 128). grid = 392.
// ---------------------------------------------------------------------------
__global__ __launch_bounds__(256) void q_gemm2(
    const float* __restrict__ x, const short* __restrict__ pk,
    const float* __restrict__ bias, short* __restrict__ out) {
  __shared__ short bs[8 * 512];
  __shared__ float sb[128];
  const int tid = threadIdx.x, w_id = tid >> 6, lane = tid & 63;
  const int l15 = lane & 15, gq = lane >> 4;
  const int mt = blockIdx.x;
  if (tid < 128) sb[tid] = bias[tid];
  const int arow = mt * 64 + w_id * 16 + l15;
  const int b = arow / 49, qi = arow % 49;
  const int n = 28 * (qi / 7) + 2 * (qi % 7);
  const float* xrow = x + ((size_t)b * 196 + n) * 256;

  f32x4 acc[8];
#pragma unroll
  for (int j = 0; j < 8; ++j) acc[j] = zero4();

  for (int c = 0; c < 8; ++c) {
    for (int seg = w_id; seg < 8; seg += 4)
      gload_lds16(pk + ((size_t)(c * 8 + seg) * 64 + lane) * 8, &bs[seg * 512]);
    const float4 u0 = *reinterpret_cast<const float4*>(xrow + c * 32 + gq * 8);
    const float4 u1 = *reinterpret_cast<const float4*>(xrow + c * 32 + gq * 8 + 4);
    bf16x8 a;
    a[0] = f2bf(u0.x); a[1] = f2bf(u0.y); a[2] = f2bf(u0.z); a[3] = f2bf(u0.w);
    a[4] = f2bf(u1.x); a[5] = f2bf(u1.y); a[6] = f2bf(u1.z); a[7] = f2bf(u1.w);
    __syncthreads();
#pragma unroll
    for (int j = 0; j < 8; ++j) {
      bf16x8 bj = *reinterpret_cast<const bf16x8*>(&bs[(j * 64 + lane) * 8]);
      acc[j] = mfma_bf16(a, bj, acc[j]);
    }
    __syncthreads();
  }
  const int orow = mt * 64 + w_id * 16 + gq * 4;
#pragma unroll
  for (int j = 0; j < 8; ++j) {
    int ch = j * 16 + l15;
    float bb = sb[ch];
#pragma unroll
    for (int r = 0; r < 4; ++r)
      out[(size_t)(orow + r) * 128 + ch] = f2bf(acc[j][r] + bb);
  }
}

// ---------------------------------------------------------------------------
// Kernel 3: swapped-operand attention; V^T slab gload_lds-staged, K from
// compact k_ws, P in registers. grid = 4096 (b,h), 256 thr.
// ---------------------------------------------------------------------------
__global__ __launch_bounds__(256) void attn3_k(
    const short* __restrict__ k_ws, const short* __restrict__ vT_ws,
    const short* __restrict__ qw, const float* __restrict__ ab,
    short* __restrict__ out) {
  __shared__ short vt[6304];   // [32][196] packed (12544 B) + 64 B guard
  const int b = blockIdx.x >> 3, h = blockIdx.x & 7;
  const int tid = threadIdx.x, w_id = tid >> 6, lane = tid & 63;
  const int l15 = lane & 15, g = lane >> 4;

  if (tid < 16) *reinterpret_cast<unsigned int*>(&vt[6272 + tid * 2]) = 0u;

  const short* vsrc = vT_ws + (size_t)(b * 8 + h) * 6272;
  for (int s = w_id; s < 13; s += 4) {
    if (s * 64 + lane < 784)
      gload_lds16(vsrc + (size_t)(s * 64 + lane) * 8, &vt[s * 512]);
  }

  const short* kslab = k_ws + (size_t)(b * 8 + h) * 3136;   // [196][16]

  const int q = w_id * 16 + l15;
  const bool qok = q < 49;
  bf16x8 bq = zero8();
  if (g < 2 && qok)
    bq = *reinterpret_cast<const bf16x8*>(
        qw + ((size_t)b * 49 + q) * 128 + h * 16 + g * 8);

  f32x4 s[13];
#pragma unroll
  for (int t = 0; t < 13; ++t) {
    int n_a = (t >> 1) * 32 + (l15 >> 2) * 8 + (t & 1) * 4 + (l15 & 3);
    bf16x8 ak = zero8();
    if (g < 2 && n_a < 196)
      ak = *reinterpret_cast<const bf16x8*>(kslab + (size_t)n_a * 16 + g * 8);
    s[t] = mfma_bf16(ak, bq, zero4());
  }

  const float* abrow = ab + ((size_t)h * 49 + (qok ? q : 0)) * 196;
#pragma unroll
  for (int t = 0; t < 13; ++t) {
    int nb = (t >> 1) * 32 + g * 8 + (t & 1) * 4;
    if (nb < 196) {
      const float4 bi = *reinterpret_cast<const float4*>(abrow + nb);
      s[t][0] = s[t][0] * 0.25f + bi.x;
      s[t][1] = s[t][1] * 0.25f + bi.y;
      s[t][2] = s[t][2] * 0.25f + bi.z;
      s[t][3] = s[t][3] * 0.25f + bi.w;
    } else {
      s[t][0] = -1e30f; s[t][1] = -1e30f; s[t][2] = -1e30f; s[t][3] = -1e30f;
    }
  }

  float mx = s[0][0];
#pragma unroll
  for (int t = 0; t < 13; ++t)
    mx = fmaxf(mx, fmaxf(fmaxf(s[t][0], s[t][1]), fmaxf(s[t][2], s[t][3])));
  mx = fmaxf(mx, __shfl_xor(mx, 16, 64));
  mx = fmaxf(mx, __shfl_xor(mx, 32, 64));
  float sum = 0.f;
#pragma unroll
  for (int t = 0; t < 13; ++t) {
#pragma unroll
    for (int r = 0; r < 4; ++r) {
      float e = __expf(s[t][r] - mx);
      s[t][r] = e;
      sum += e;
    }
  }
  sum += __shfl_xor(sum, 16, 64);
  sum += __shfl_xor(sum, 32, 64);
  const float inv = 1.f / sum;

  unsigned int pkr[14][2];
#pragma unroll
  for (int t = 0; t < 13; ++t) {
    pkr[t][0] = pack2bf(s[t][0] * inv, s[t][1] * inv);
    pkr[t][1] = pack2bf(s[t][2] * inv, s[t][3] * inv);
  }
  pkr[13][0] = 0u; pkr[13][1] = 0u;

  __syncthreads();   // V^T staged

  f32x4 o0 = zero4(), o1 = zero4();
#pragma unroll
  for (int c = 0; c < 7; ++c) {
    u32x4 bp_u;
    bp_u[0] = pkr[2 * c][0];     bp_u[1] = pkr[2 * c][1];
    bp_u[2] = pkr[2 * c + 1][0]; bp_u[3] = pkr[2 * c + 1][1];
    bf16x8 bp = __builtin_bit_cast(bf16x8, bp_u);
    bf16x8 a0 = lds8(&vt[l15 * 196 + c * 32 + g * 8]);
    bf16x8 a1 = lds8(&vt[(16 + l15) * 196 + c * 32 + g * 8]);
    o0 = mfma_bf16(a0, bp, o0);
    o1 = mfma_bf16(a1, bp, o1);
  }

  if (qok) {
    short* op = out + (((size_t)b * 49 + q) * 256 + h * 32 + g * 4);
    short4v v0, v1;
#pragma unroll
    for (int r = 0; r < 4; ++r) {
      float x0 = o0[r];
      v0[r] = f2bf(x0 * fminf(fmaxf(x0 + 3.f, 0.f), 6.f) * (1.f / 6.f));
      float x1 = o1[r];
      v1[r] = f2bf(x1 * fminf(fmaxf(x1 + 3.f, 0.f), 6.f) * (1.f / 6.f));
    }
    *reinterpret_cast<short4v*>(op) = v0;
    *reinterpret_cast<short4v*>(op + 16) = v1;
  }
}

// ---------------------------------------------------------------------------
// Kernel 4: out = at @ pk_p + bias -> f32 (B*49, 512). grid = 392*2.
// ---------------------------------------------------------------------------
__global__ __launch_bounds__(256) void p_gemm2(
    const short* __restrict__ a_in, const short* __restrict__ pk,
    const float* __restrict__ bias, float* __restrict__ out) {
  __shared__ short bs[16 * 512];
  __shared__ float sb[256];
  const int tid = threadIdx.x, w_id = tid >> 6, lane = tid & 63;
  const int l15 = lane & 15, gq = lane >> 4;
  const int half = blockIdx.x & 1;
  const int mt = blockIdx.x >> 1;
  for (int i = tid; i < 256; i += 256) sb[i] = bias[half * 256 + i];
  const int arow = mt * 64 + w_id * 16 + l15;
  const short* arp = a_in + (size_t)arow * 256;

  f32x4 acc[16];
#pragma unroll
  for (int j = 0; j < 16; ++j) acc[j] = zero4();

  for (int c = 0; c < 8; ++c) {
    for (int seg = w_id; seg < 16; seg += 4)
      gload_lds16(pk + ((size_t)(c * 32 + half * 16 + seg) * 64 + lane) * 8,
                  &bs[seg * 512]);
    bf16x8 a = *reinterpret_cast<const bf16x8*>(arp + c * 32 + gq * 8);
    __syncthreads();
#pragma unroll
    for (int j = 0; j < 16; ++j) {
      bf16x8 bj = *reinterpret_cast<const bf16x8*>(&bs[(j * 64 + lane) * 8]);
      acc[j] = mfma_bf16(a, bj, acc[j]);
    }
    __syncthreads();
  }
  const int orow = mt * 64 + w_id * 16 + gq * 4;
#pragma unroll
  for (int j = 0; j < 16; ++j) {
    int chl = j * 16 + l15;
    float bb = sb[chl];
    int och = half * 256 + chl;
#pragma unroll
    for (int r = 0; r < 4; ++r)
      out[(size_t)(orow + r) * 512 + och] = acc[j][r] + bb;
  }
}

// ---------------------------------------------------------------------------
extern "C" void kernel_launch(void* const* d_in, const int* in_sizes, int n_in,
                              void* d_out, int out_size, void* d_ws, size_t ws_size,
                              hipStream_t stream) {
  const float* x    = (const float*)d_in[0];
  const float* w_kv = (const float*)d_in[1];
  const float* kv_g = (const float*)d_in[2];
  const float* kv_b = (const float*)d_in[3];
  const float* kv_m = (const float*)d_in[4];
  const float* kv_v = (const float*)d_in[5];
  const float* w_q  = (const float*)d_in[6];
  const float* q_g  = (const float*)d_in[7];
  const float* q_b  = (const float*)d_in[8];
  const float* q_m  = (const float*)d_in[9];
  const float* q_v  = (const float*)d_in[10];
  const float* w_p  = (const float*)d_in[11];
  const float* p_g  = (const float*)d_in[12];
  const float* p_b  = (const float*)d_in[13];
  const float* p_m  = (const float*)d_in[14];
  const float* p_v  = (const float*)d_in[15];
  const float* ab_t = (const float*)d_in[16];
  const int*   idxs = (const int*)d_in[17];
  const int n_off = in_sizes[16] / 8;

  char* ws = (char*)d_ws;
  short* pk_kv  = (short*)(ws);                    //    196,608
  short* pk_q   = (short*)(ws + 196608);           //     65,536
  short* pk_p   = (short*)(ws + 262144);           //    262,144
  float* bs_kv  = (float*)(ws + 524288);           //      1,536
  float* bs_q   = (float*)(ws + 525824);           //        512
  float* bs_p   = (float*)(ws + 526336);           //      2,048
  float* ab_ws  = (float*)(ws + 528384);           //    307,328 -> 835,712
  short* k_ws   = (short*)(ws + 835712);           // 25,690,112 -> 26,525,824
  short* vT_ws  = (short*)(ws + 26525824);         // 51,380,224 -> 77,906,048
  short* q_ws   = (short*)(ws + 77906048);         //  6,422,528 -> 84,328,576
  short* at_ws  = (short*)(ws + 84328576);         // 12,845,056 -> 97,173,632

  pack_w_k<<<dim3(48), dim3(256), 0, stream>>>(w_kv, kv_g, kv_b, kv_m, kv_v, pk_kv, bs_kv, 384);
  pack_w_k<<<dim3(16), dim3(256), 0, stream>>>(w_q, q_g, q_b, q_m, q_v, pk_q, bs_q, 128);
  pack_w_k<<<dim3(64), dim3(256), 0, stream>>>(w_p, p_g, p_b, p_m, p_v, pk_p, bs_p, 512);
  ab_gather_k<<<dim3(392), dim3(256), 0, stream>>>(ab_t, idxs, ab_ws, n_off);

  kv_gemm5<<<dim3(1568), dim3(512), 0, stream>>>(x, pk_kv, bs_kv, k_ws, vT_ws);
  q_gemm2<<<dim3(392), dim3(256), 0, stream>>>(x, pk_q, bs_q, q_ws);
  attn3_k<<<dim3(4096), dim3(256), 0, stream>>>(k_ws, vT_ws, q_ws, ab_ws, at_ws);
  p_gemm2<<<dim3(784), dim3(256), 0, stream>>>(at_ws, pk_p, bs_p, (float*)d_out);
}

// Round 10
// 153.206 us; speedup vs baseline: 2.4377x; 1.0050x over previous
//
#include <hip/hip_runtime.h>

typedef __attribute__((ext_vector_type(8))) short bf16x8;
typedef __attribute__((ext_vector_type(4))) float f32x4;
typedef __attribute__((ext_vector_type(4))) short short4v;
typedef __attribute__((ext_vector_type(4))) unsigned int u32x4;

#define DEVFN static __device__ __forceinline__

DEVFN short f2bf(float f) {
  unsigned int u = __builtin_bit_cast(unsigned int, f);
  unsigned int r = (u + 0x7FFFu + ((u >> 16) & 1u)) >> 16;   // RNE
  return (short)r;
}

DEVFN unsigned int pack2bf(float a, float b) {
  unsigned int lo = (unsigned int)(unsigned short)f2bf(a);
  unsigned int hi = (unsigned int)(unsigned short)f2bf(b);
  return lo | (hi << 16);
}

DEVFN f32x4 mfma_bf16(bf16x8 a, bf16x8 b, f32x4 c) {
  return __builtin_amdgcn_mfma_f32_16x16x32_bf16(a, b, c, 0, 0, 0);
}

DEVFN f32x4 zero4() { f32x4 z = {0.f, 0.f, 0.f, 0.f}; return z; }
DEVFN bf16x8 zero8() { bf16x8 z = {0,0,0,0,0,0,0,0}; return z; }

DEVFN void gload_lds16(const void* g, void* l) {
  __builtin_amdgcn_global_load_lds(
      (const __attribute__((address_space(1))) unsigned int*)g,
      (__attribute__((address_space(3))) unsigned int*)l, 16, 0, 0);
}

DEVFN bf16x8 lds8(const short* p) {
  short4v lo = *reinterpret_cast<const short4v*>(p);
  short4v hi = *reinterpret_cast<const short4v*>(p + 4);
  bf16x8 r;
  r[0] = lo[0]; r[1] = lo[1]; r[2] = lo[2]; r[3] = lo[3];
  r[4] = hi[0]; r[5] = hi[1]; r[6] = hi[2]; r[7] = hi[3];
  return r;
}

DEVFN bf16x8 cvt8v(float4 u0, float4 u1) {
  bf16x8 r;
  r[0] = f2bf(u0.x); r[1] = f2bf(u0.y); r[2] = f2bf(u0.z); r[3] = f2bf(u0.w);
  r[4] = f2bf(u1.x); r[5] = f2bf(u1.y); r[6] = f2bf(u1.z); r[7] = f2bf(u1.w);
  return r;
}

// ---------------------------------------------------------------------------
// Weight pack: fold BN scale, cvt bf16, fragment-major layout
// pk[((c*(O/16)+j)*64+lane)*8+e] = w[j*16+(lane&15)][c*32+(lane>>4)*8+e]*s
// ---------------------------------------------------------------------------
__global__ void pack_w_k(const float* __restrict__ w, const float* __restrict__ g,
                         const float* __restrict__ b, const float* __restrict__ m,
                         const float* __restrict__ v, short* __restrict__ pk,
                         float* __restrict__ bias, int O) {
  const int t = blockIdx.x * 256 + threadIdx.x;
  const int nt = O >> 4;
  const int total = nt * 8 * 64;
  if (t < total) {
    int lane = t & 63;
    int j = (t >> 6) % nt;
    int c = (t >> 6) / nt;
    int row = j * 16 + (lane & 15);
    int col = c * 32 + (lane >> 4) * 8;
    float s = g[row] * rsqrtf(v[row] + 1e-5f);
    const float* wp = w + (size_t)row * 256 + col;
    short* o = pk + (size_t)t * 8;
#pragma unroll
    for (int e = 0; e < 8; ++e) o[e] = f2bf(wp[e] * s);
  }
  if (t < O) {
    float s = g[t] * rsqrtf(v[t] + 1e-5f);
    bias[t] = b[t] - m[t] * s;
  }
}

// ---------------------------------------------------------------------------
// ab_full[h][q][n] = ab_table[h][bias_idxs[q][n]]
// ---------------------------------------------------------------------------
__global__ void ab_gather_k(const float* __restrict__ tab,
                            const int* __restrict__ idxs,
                            float* __restrict__ out, int n_off) {
  const int hq = blockIdx.x;
  const int h = hq / 49, q = hq % 49;
  const int t = threadIdx.x;
  if (t < 196)
    out[(size_t)hq * 196 + t] = tab[h * n_off + idxs[q * 196 + t]];
}

// ---------------------------------------------------------------------------
// Kernel 1 (NEW): kv gemm with zero-VGPR f32 staging.
// x-tile (64 rows x 256 f32) staged RAW via global_load_lds into LDS with
// row-stride 1040 B (odd 16B-slot count -> dense bank schedule, no swizzle).
// One barrier; then wave w (= head w) computes {K, V0, V1} x 4 m-subtiles,
// converting f32->bf16 at fragment-read time. grid = 1568, 512 thr.
// ---------------------------------------------------------------------------
__global__ __launch_bounds__(512, 4) void kv_gemm6(
    const float* __restrict__ x, const short* __restrict__ pk,
    const float* __restrict__ bias, short* __restrict__ k_out,
    short* __restrict__ vT_out) {
  __shared__ float xsf[64 * 260];   // 66,560 B
  const int tid = threadIdx.x, w = tid >> 6, lane = tid & 63;
  const int l15 = lane & 15, g = lane >> 4;
  const int mt = blockIdx.x;

  // ---- stage: seg s == row s; lane = 16B granule; no VGPR round-trip ----
  const float* xb = x + (size_t)mt * 64 * 256;
#pragma unroll
  for (int s8 = 0; s8 < 8; ++s8) {
    const int row = w * 8 + s8;
    gload_lds16(xb + (size_t)row * 256 + lane * 4, &xsf[row * 260]);
  }
  __syncthreads();   // drains vmcnt; the ONLY barrier

  // ---- main loop: no further syncs ----
  f32x4 acc[4][3];
#pragma unroll
  for (int m = 0; m < 4; ++m) {
    acc[m][0] = zero4(); acc[m][1] = zero4(); acc[m][2] = zero4();
  }
#pragma unroll
  for (int c = 0; c < 8; ++c) {
    bf16x8 wf0 = *reinterpret_cast<const bf16x8*>(pk + ((size_t)(c * 24 + 3 * w) * 64 + lane) * 8);
    bf16x8 wf1 = *reinterpret_cast<const bf16x8*>(pk + ((size_t)(c * 24 + 3 * w + 1) * 64 + lane) * 8);
    bf16x8 wf2 = *reinterpret_cast<const bf16x8*>(pk + ((size_t)(c * 24 + 3 * w + 2) * 64 + lane) * 8);
#pragma unroll
    for (int m = 0; m < 4; ++m) {
      const int row = m * 16 + l15;
      const float* p = &xsf[row * 260 + c * 32 + g * 8];
      float4 u0 = *reinterpret_cast<const float4*>(p);
      float4 u1 = *reinterpret_cast<const float4*>(p + 4);
      bf16x8 a = cvt8v(u0, u1);
      acc[m][0] = mfma_bf16(a, wf0, acc[m][0]);
      acc[m][1] = mfma_bf16(a, wf1, acc[m][1]);
      acc[m][2] = mfma_bf16(a, wf2, acc[m][2]);
    }
  }

  // ---- epilogue: K -> [b][h][196][16], V^T -> [b][h][32][196] ----
  const float bvK = bias[(3 * w) * 16 + l15];
  const float bv1 = bias[(3 * w + 1) * 16 + l15];
  const float bv2 = bias[(3 * w + 2) * 16 + l15];
#pragma unroll
  for (int m = 0; m < 4; ++m) {
    const int row0 = mt * 64 + m * 16 + g * 4;
    const int bb_ = row0 / 196, n0 = row0 % 196;   // 4-row quad never straddles
    short* kp = k_out + ((size_t)(bb_ * 8 + w) * 196 + n0) * 16 + l15;
#pragma unroll
    for (int r = 0; r < 4; ++r) kp[r * 16] = f2bf(acc[m][0][r] + bvK);
    short4v sv;
#pragma unroll
    for (int r = 0; r < 4; ++r) sv[r] = f2bf(acc[m][1][r] + bv1);
    *reinterpret_cast<short4v*>(
        vT_out + ((size_t)(bb_ * 8 + w) * 32 + l15) * 196 + n0) = sv;
#pragma unroll
    for (int r = 0; r < 4; ++r) sv[r] = f2bf(acc[m][2][r] + bv2);
    *reinterpret_cast<short4v*>(
        vT_out + ((size_t)(bb_ * 8 + w) * 32 + 16 + l15) * 196 + n0) = sv;
  }
}

// ---------------------------------------------------------------------------
// Kernel 2: q = xs @ pk_q + bias -> bf16 (B*49, 128). grid = 392.
// ---------------------------------------------------------------------------
__global__ __launch_bounds__(256) void q_gemm2(
    const float* __restrict__ x, const short* __restrict__ pk,
    const float* __restrict__ bias, short* __restrict__ out) {
  __shared__ short bs[8 * 512];
  __shared__ float sb[128];
  const int tid = threadIdx.x, w_id = tid >> 6, lane = tid & 63;
  const int l15 = lane & 15, gq = lane >> 4;
  const int mt = blockIdx.x;
  if (tid < 128) sb[tid] = bias[tid];
  const int arow = mt * 64 + w_id * 16 + l15;
  const int b = arow / 49, qi = arow % 49;
  const int n = 28 * (qi / 7) + 2 * (qi % 7);
  const float* xrow = x + ((size_t)b * 196 + n) * 256;

  f32x4 acc[8];
#pragma unroll
  for (int j = 0; j < 8; ++j) acc[j] = zero4();

  for (int c = 0; c < 8; ++c) {
    for (int seg = w_id; seg < 8; seg += 4)
      gload_lds16(pk + ((size_t)(c * 8 + seg) * 64 + lane) * 8, &bs[seg * 512]);
    const float4 u0 = *reinterpret_cast<const float4*>(xrow + c * 32 + gq * 8);
    const float4 u1 = *reinterpret_cast<const float4*>(xrow + c * 32 + gq * 8 + 4);
    bf16x8 a = cvt8v(u0, u1);
    __syncthreads();
#pragma unroll
    for (int j = 0; j < 8; ++j) {
      bf16x8 bj = *reinterpret_cast<const bf16x8*>(&bs[(j * 64 + lane) * 8]);
      acc[j] = mfma_bf16(a, bj, acc[j]);
    }
    __syncthreads();
  }
  const int orow = mt * 64 + w_id * 16 + gq * 4;
#pragma unroll
  for (int j = 0; j < 8; ++j) {
    int ch = j * 16 + l15;
    float bb = sb[ch];
#pragma unroll
    for (int r = 0; r < 4; ++r)
      out[(size_t)(orow + r) * 128 + ch] = f2bf(acc[j][r] + bb);
  }
}

// ---------------------------------------------------------------------------
// Kernel 3: swapped-operand attention; V^T slab gload_lds-staged, K from
// compact k_ws, P in registers. grid = 4096 (b,h), 256 thr.
// ---------------------------------------------------------------------------
__global__ __launch_bounds__(256) void attn3_k(
    const short* __restrict__ k_ws, const short* __restrict__ vT_ws,
    const short* __restrict__ qw, const float* __restrict__ ab,
    short* __restrict__ out) {
  __shared__ short vt[6304];   // [32][196] packed (12544 B) + 64 B guard
  const int b = blockIdx.x >> 3, h = blockIdx.x & 7;
  const int tid = threadIdx.x, w_id = tid >> 6, lane = tid & 63;
  const int l15 = lane & 15, g = lane >> 4;

  if (tid < 16) *reinterpret_cast<unsigned int*>(&vt[6272 + tid * 2]) = 0u;

  const short* vsrc = vT_ws + (size_t)(b * 8 + h) * 6272;
  for (int s = w_id; s < 13; s += 4) {
    if (s * 64 + lane < 784)
      gload_lds16(vsrc + (size_t)(s * 64 + lane) * 8, &vt[s * 512]);
  }

  const short* kslab = k_ws + (size_t)(b * 8 + h) * 3136;   // [196][16]

  const int q = w_id * 16 + l15;
  const bool qok = q < 49;
  bf16x8 bq = zero8();
  if (g < 2 && qok)
    bq = *reinterpret_cast<const bf16x8*>(
        qw + ((size_t)b * 49 + q) * 128 + h * 16 + g * 8);

  f32x4 s[13];
#pragma unroll
  for (int t = 0; t < 13; ++t) {
    int n_a = (t >> 1) * 32 + (l15 >> 2) * 8 + (t & 1) * 4 + (l15 & 3);
    bf16x8 ak = zero8();
    if (g < 2 && n_a < 196)
      ak = *reinterpret_cast<const bf16x8*>(kslab + (size_t)n_a * 16 + g * 8);
    s[t] = mfma_bf16(ak, bq, zero4());
  }

  const float* abrow = ab + ((size_t)h * 49 + (qok ? q : 0)) * 196;
#pragma unroll
  for (int t = 0; t < 13; ++t) {
    int nb = (t >> 1) * 32 + g * 8 + (t & 1) * 4;
    if (nb < 196) {
      const float4 bi = *reinterpret_cast<const float4*>(abrow + nb);
      s[t][0] = s[t][0] * 0.25f + bi.x;
      s[t][1] = s[t][1] * 0.25f + bi.y;
      s[t][2] = s[t][2] * 0.25f + bi.z;
      s[t][3] = s[t][3] * 0.25f + bi.w;
    } else {
      s[t][0] = -1e30f; s[t][1] = -1e30f; s[t][2] = -1e30f; s[t][3] = -1e30f;
    }
  }

  float mx = s[0][0];
#pragma unroll
  for (int t = 0; t < 13; ++t)
    mx = fmaxf(mx, fmaxf(fmaxf(s[t][0], s[t][1]), fmaxf(s[t][2], s[t][3])));
  mx = fmaxf(mx, __shfl_xor(mx, 16, 64));
  mx = fmaxf(mx, __shfl_xor(mx, 32, 64));
  float sum = 0.f;
#pragma unroll
  for (int t = 0; t < 13; ++t) {
#pragma unroll
    for (int r = 0; r < 4; ++r) {
      float e = __expf(s[t][r] - mx);
      s[t][r] = e;
      sum += e;
    }
  }
  sum += __shfl_xor(sum, 16, 64);
  sum += __shfl_xor(sum, 32, 64);
  const float inv = 1.f / sum;

  unsigned int pkr[14][2];
#pragma unroll
  for (int t = 0; t < 13; ++t) {
    pkr[t][0] = pack2bf(s[t][0] * inv, s[t][1] * inv);
    pkr[t][1] = pack2bf(s[t][2] * inv, s[t][3] * inv);
  }
  pkr[13][0] = 0u; pkr[13][1] = 0u;

  __syncthreads();   // V^T staged

  f32x4 o0 = zero4(), o1 = zero4();
#pragma unroll
  for (int c = 0; c < 7; ++c) {
    u32x4 bp_u;
    bp_u[0] = pkr[2 * c][0];     bp_u[1] = pkr[2 * c][1];
    bp_u[2] = pkr[2 * c + 1][0]; bp_u[3] = pkr[2 * c + 1][1];
    bf16x8 bp = __builtin_bit_cast(bf16x8, bp_u);
    bf16x8 a0 = lds8(&vt[l15 * 196 + c * 32 + g * 8]);
    bf16x8 a1 = lds8(&vt[(16 + l15) * 196 + c * 32 + g * 8]);
    o0 = mfma_bf16(a0, bp, o0);
    o1 = mfma_bf16(a1, bp, o1);
  }

  if (qok) {
    short* op = out + (((size_t)b * 49 + q) * 256 + h * 32 + g * 4);
    short4v v0, v1;
#pragma unroll
    for (int r = 0; r < 4; ++r) {
      float x0 = o0[r];
      v0[r] = f2bf(x0 * fminf(fmaxf(x0 + 3.f, 0.f), 6.f) * (1.f / 6.f));
      float x1 = o1[r];
      v1[r] = f2bf(x1 * fminf(fmaxf(x1 + 3.f, 0.f), 6.f) * (1.f / 6.f));
    }
    *reinterpret_cast<short4v*>(op) = v0;
    *reinterpret_cast<short4v*>(op + 16) = v1;
  }
}

// ---------------------------------------------------------------------------
// Kernel 4: out = at @ pk_p + bias -> f32 (B*49, 512). grid = 392*2.
// ---------------------------------------------------------------------------
__global__ __launch_bounds__(256) void p_gemm2(
    const short* __restrict__ a_in, const short* __restrict__ pk,
    const float* __restrict__ bias, float* __restrict__ out) {
  __shared__ short bs[16 * 512];
  __shared__ float sb[256];
  const int tid = threadIdx.x, w_id = tid >> 6, lane = tid & 63;
  const int l15 = lane & 15, gq = lane >> 4;
  const int half = blockIdx.x & 1;
  const int mt = blockIdx.x >> 1;
  for (int i = tid; i < 256; i += 256) sb[i] = bias[half * 256 + i];
  const int arow = mt * 64 + w_id * 16 + l15;
  const short* arp = a_in + (size_t)arow * 256;

  f32x4 acc[16];
#pragma unroll
  for (int j = 0; j < 16; ++j) acc[j] = zero4();

  for (int c = 0; c < 8; ++c) {
    for (int seg = w_id; seg < 16; seg += 4)
      gload_lds16(pk + ((size_t)(c * 32 + half * 16 + seg) * 64 + lane) * 8,
                  &bs[seg * 512]);
    bf16x8 a = *reinterpret_cast<const bf16x8*>(arp + c * 32 + gq * 8);
    __syncthreads();
#pragma unroll
    for (int j = 0; j < 16; ++j) {
      bf16x8 bj = *reinterpret_cast<const bf16x8*>(&bs[(j * 64 + lane) * 8]);
      acc[j] = mfma_bf16(a, bj, acc[j]);
    }
    __syncthreads();
  }
  const int orow = mt * 64 + w_id * 16 + gq * 4;
#pragma unroll
  for (int j = 0; j < 16; ++j) {
    int chl = j * 16 + l15;
    float bb = sb[chl];
    int och = half * 256 + chl;
#pragma unroll
    for (int r = 0; r < 4; ++r)
      out[(size_t)(orow + r) * 512 + och] = acc[j][r] + bb;
  }
}

// ---------------------------------------------------------------------------
extern "C" void kernel_launch(void* const* d_in, const int* in_sizes, int n_in,
                              void* d_out, int out_size, void* d_ws, size_t ws_size,
                              hipStream_t stream) {
  const float* x    = (const float*)d_in[0];
  const float* w_kv = (const float*)d_in[1];
  const float* kv_g = (const float*)d_in[2];
  const float* kv_b = (const float*)d_in[3];
  const float* kv_m = (const float*)d_in[4];
  const float* kv_v = (const float*)d_in[5];
  const float* w_q  = (const float*)d_in[6];
  const float* q_g  = (const float*)d_in[7];
  const float* q_b  = (const float*)d_in[8];
  const float* q_m  = (const float*)d_in[9];
  const float* q_v  = (const float*)d_in[10];
  const float* w_p  = (const float*)d_in[11];
  const float* p_g  = (const float*)d_in[12];
  const float* p_b  = (const float*)d_in[13];
  const float* p_m  = (const float*)d_in[14];
  const float* p_v  = (const float*)d_in[15];
  const float* ab_t = (const float*)d_in[16];
  const int*   idxs = (const int*)d_in[17];
  const int n_off = in_sizes[16] / 8;

  char* ws = (char*)d_ws;
  short* pk_kv  = (short*)(ws);                    //    196,608
  short* pk_q   = (short*)(ws + 196608);           //     65,536
  short* pk_p   = (short*)(ws + 262144);           //    262,144
  float* bs_kv  = (float*)(ws + 524288);           //      1,536
  float* bs_q   = (float*)(ws + 525824);           //        512
  float* bs_p   = (float*)(ws + 526336);           //      2,048
  float* ab_ws  = (float*)(ws + 528384);           //    307,328 -> 835,712
  short* k_ws   = (short*)(ws + 835712);           // 25,690,112 -> 26,525,824
  short* vT_ws  = (short*)(ws + 26525824);         // 51,380,224 -> 77,906,048
  short* q_ws   = (short*)(ws + 77906048);         //  6,422,528 -> 84,328,576
  short* at_ws  = (short*)(ws + 84328576);         // 12,845,056 -> 97,173,632

  pack_w_k<<<dim3(48), dim3(256), 0, stream>>>(w_kv, kv_g, kv_b, kv_m, kv_v, pk_kv, bs_kv, 384);
  pack_w_k<<<dim3(16), dim3(256), 0, stream>>>(w_q, q_g, q_b, q_m, q_v, pk_q, bs_q, 128);
  pack_w_k<<<dim3(64), dim3(256), 0, stream>>>(w_p, p_g, p_b, p_m, p_v, pk_p, bs_p, 512);
  ab_gather_k<<<dim3(392), dim3(256), 0, stream>>>(ab_t, idxs, ab_ws, n_off);

  kv_gemm6<<<dim3(1568), dim3(512), 0, stream>>>(x, pk_kv, bs_kv, k_ws, vT_ws);
  q_gemm2<<<dim3(392), dim3(256), 0, stream>>>(x, pk_q, bs_q, q_ws);
  attn3_k<<<dim3(4096), dim3(256), 0, stream>>>(k_ws, vT_ws, q_ws, ab_ws, at_ws);
  p_gemm2<<<dim3(784), dim3(256), 0, stream>>>(at_ws, pk_p, bs_p, (float*)d_out);
}